// Round 12
// baseline (233.872 us; speedup 1.0000x reference)
//
#include <hip/hip_runtime.h>
#include <stdint.h>

#define NB 64     // batch
#define NP 4096   // points per batch
#define ND 3      // dim
#define NL 128    // chain length / projections
#define NE 64     // elements per lane; one wave handles one (b,l) unit
#define WPB 4     // independent waves (units) per block

typedef uint32_t u32;
typedef _Float16 half2v __attribute__((ext_vector_type(2)));

// ---------------- JAX threefry2x32 (20 rounds) ----------------
__device__ __forceinline__ uint32_t rotl32(uint32_t v, int r) {
  return (v << r) | (v >> (32 - r));
}

__device__ __forceinline__ void threefry2x32(uint32_t k0, uint32_t k1,
                                             uint32_t c0, uint32_t c1,
                                             uint32_t& o0, uint32_t& o1) {
  uint32_t ks2 = k0 ^ k1 ^ 0x1BD11BDAu;
  uint32_t x0 = c0 + k0;
  uint32_t x1 = c1 + k1;
#define TF_RND(R) { x0 += x1; x1 = rotl32(x1, (R)); x1 ^= x0; }
  TF_RND(13) TF_RND(15) TF_RND(26) TF_RND(6)
  x0 += k1;  x1 += ks2 + 1u;
  TF_RND(17) TF_RND(29) TF_RND(16) TF_RND(24)
  x0 += ks2; x1 += k0 + 2u;
  TF_RND(13) TF_RND(15) TF_RND(26) TF_RND(6)
  x0 += k0;  x1 += k1 + 3u;
  TF_RND(17) TF_RND(29) TF_RND(16) TF_RND(24)
  x0 += k1;  x1 += ks2 + 4u;
  TF_RND(13) TF_RND(15) TF_RND(26) TF_RND(6)
  x0 += ks2; x1 += k0 + 5u;
#undef TF_RND
  o0 = x0; o1 = x1;
}

// ---------------- XLA ErfInv32 ----------------
__device__ __forceinline__ float erfinv_f(float x) {
  float w = -log1pf(-x * x);
  float p;
  if (w < 5.0f) {
    w = w - 2.5f;
    p = 2.81022636e-08f;
    p = fmaf(p, w, 3.43273939e-07f);
    p = fmaf(p, w, -3.5233877e-06f);
    p = fmaf(p, w, -4.39150654e-06f);
    p = fmaf(p, w, 0.00021858087f);
    p = fmaf(p, w, -0.00125372503f);
    p = fmaf(p, w, -0.00417768164f);
    p = fmaf(p, w, 0.246640727f);
    p = fmaf(p, w, 1.50140941f);
  } else {
    w = sqrtf(w) - 3.0f;
    p = -0.000200214257f;
    p = fmaf(p, w, 0.000100950558f);
    p = fmaf(p, w, 0.00134934322f);
    p = fmaf(p, w, -0.00367342844f);
    p = fmaf(p, w, 0.00573950773f);
    p = fmaf(p, w, -0.0076224613f);
    p = fmaf(p, w, 0.00943887047f);
    p = fmaf(p, w, 1.00167406f);
    p = fmaf(p, w, 2.83297682f);
  }
  return p * x;
}

__device__ __forceinline__ float bits_to_normal(uint32_t bits) {
  float f = __uint_as_float((bits >> 9) | 0x3F800000u) - 1.0f;  // [0,1)
  const float LO = -0.99999994f;  // nextafter(-1, 0)
  float u = fmaf(f, 2.0f, LO);
  u = fmaxf(LO, u);
  return 1.41421354f * erfinv_f(u);
}

__device__ __forceinline__ float bits_to_unif01(uint32_t bits) {
  float f = __uint_as_float((bits >> 9) | 0x3F800000u) - 1.0f;
  return fmaxf(0.0f, f);
}

// ---------------- Kernel A: thetas (normalized) + log-uniforms ----------
__global__ __launch_bounds__(128) void rng_kernel(float* __restrict__ theta,
                                                  float* __restrict__ logu) {
  const int l = blockIdx.x;
  const int tid = threadIdx.x;

  uint32_t kl0, kl1;
  threefry2x32(0u, 42u, 0u, (uint32_t)l, kl0, kl1);

  uint32_t na0 = kl0, na1 = kl1;
  uint32_t nb0 = 0u, nb1 = 0u;
  if (l > 0) {
    uint32_t a0, b0, a1, b1;
    threefry2x32(kl0, kl1, 0u, 2u, a0, b0);
    threefry2x32(kl0, kl1, 1u, 3u, a1, b1);
    na0 = a0; na1 = a1;
    nb0 = b0; nb1 = b1;
  }

  __shared__ float vals[NB * ND];
  if (tid < 96) {
    uint32_t o0, o1;
    threefry2x32(na0, na1, (uint32_t)tid, (uint32_t)(96 + tid), o0, o1);
    vals[tid] = bits_to_normal(o0);
    vals[96 + tid] = bits_to_normal(o1);
  }
  __syncthreads();

  if (tid < NB) {
    float v0 = vals[tid * 3 + 0];
    float v1 = vals[tid * 3 + 1];
    float v2 = vals[tid * 3 + 2];
    float s = sqrtf(v0 * v0 + v1 * v1 + v2 * v2);
    float* tp = theta + ((size_t)l * NB + tid) * 3;
    tp[0] = v0 / s;
    tp[1] = v1 / s;
    tp[2] = v2 / s;
  }

  if (l > 0 && tid < 32) {
    uint32_t o0, o1;
    threefry2x32(nb0, nb1, (uint32_t)tid, (uint32_t)(32 + tid), o0, o1);
    logu[l * NB + tid] = logf(bits_to_unif01(o0));
    logu[l * NB + 32 + tid] = logf(bits_to_unif01(o1));
  }
}

// ---------------- packed primitives ----------------
__device__ __forceinline__ u32 pkmin(u32 a, u32 b) {
  u32 d; asm("v_pk_min_f16 %0, %1, %2" : "=v"(d) : "v"(a), "v"(b)); return d;
}
__device__ __forceinline__ u32 pkmax(u32 a, u32 b) {
  u32 d; asm("v_pk_max_f16 %0, %1, %2" : "=v"(d) : "v"(a), "v"(b)); return d;
}

__device__ __forceinline__ void ceA(u32& a, u32& b) {
  u32 mn = pkmin(a, b), mx = pkmax(a, b); a = mn; b = mx;
}
__device__ __forceinline__ void ceD(u32& a, u32& b) {
  u32 mn = pkmin(a, b), mx = pkmax(a, b); a = mx; b = mn;
}

__device__ __forceinline__ u32 fmask(u32 d) {  // d in {0,1}
  return (d << 31) | (d << 15);
}

__device__ __forceinline__ void flip64(u32 (&r)[NE], u32 mask) {
#pragma unroll
  for (int w = 0; w < NE; ++w) r[w] ^= mask;
}

// in-thread ascending tail: stages j = 32,16,8,4,2,1 over the 64 regs
__device__ __forceinline__ void tail64(u32 (&r)[NE]) {
#pragma unroll
  for (int j = 32; j >= 1; j >>= 1)
#pragma unroll
    for (int v = 0; v < NE; ++v)
      if (!(v & j)) ceA(r[v], r[v | j]);
}

__device__ __forceinline__ void ce_keep(u32& a, u32 p, bool km) {
  u32 mn = pkmin(a, p), mx = pkmax(a, p);
  a = km ? mn : mx;
}

// 16 ds_bpermute in one asm block, single waitcnt (validated rounds 5/8/9)
__device__ __forceinline__ void stage_bperm16(u32 (&r)[16], int addr, bool km) {
  u32 p0, p1, p2, p3, p4, p5, p6, p7, p8, p9, p10, p11, p12, p13, p14, p15;
  asm("ds_bpermute_b32 %0, %16, %17\n\t"
      "ds_bpermute_b32 %1, %16, %18\n\t"
      "ds_bpermute_b32 %2, %16, %19\n\t"
      "ds_bpermute_b32 %3, %16, %20\n\t"
      "ds_bpermute_b32 %4, %16, %21\n\t"
      "ds_bpermute_b32 %5, %16, %22\n\t"
      "ds_bpermute_b32 %6, %16, %23\n\t"
      "ds_bpermute_b32 %7, %16, %24\n\t"
      "ds_bpermute_b32 %8, %16, %25\n\t"
      "ds_bpermute_b32 %9, %16, %26\n\t"
      "ds_bpermute_b32 %10, %16, %27\n\t"
      "ds_bpermute_b32 %11, %16, %28\n\t"
      "ds_bpermute_b32 %12, %16, %29\n\t"
      "ds_bpermute_b32 %13, %16, %30\n\t"
      "ds_bpermute_b32 %14, %16, %31\n\t"
      "ds_bpermute_b32 %15, %16, %32\n\t"
      "s_waitcnt lgkmcnt(0)"
      : "=&v"(p0), "=&v"(p1), "=&v"(p2), "=&v"(p3),
        "=&v"(p4), "=&v"(p5), "=&v"(p6), "=&v"(p7),
        "=&v"(p8), "=&v"(p9), "=&v"(p10), "=&v"(p11),
        "=&v"(p12), "=&v"(p13), "=&v"(p14), "=&v"(p15)
      : "v"(addr),
        "v"(r[0]), "v"(r[1]), "v"(r[2]), "v"(r[3]),
        "v"(r[4]), "v"(r[5]), "v"(r[6]), "v"(r[7]),
        "v"(r[8]), "v"(r[9]), "v"(r[10]), "v"(r[11]),
        "v"(r[12]), "v"(r[13]), "v"(r[14]), "v"(r[15]));
  ce_keep(r[0], p0, km);   ce_keep(r[1], p1, km);
  ce_keep(r[2], p2, km);   ce_keep(r[3], p3, km);
  ce_keep(r[4], p4, km);   ce_keep(r[5], p5, km);
  ce_keep(r[6], p6, km);   ce_keep(r[7], p7, km);
  ce_keep(r[8], p8, km);   ce_keep(r[9], p9, km);
  ce_keep(r[10], p10, km); ce_keep(r[11], p11, km);
  ce_keep(r[12], p12, km); ce_keep(r[13], p13, km);
  ce_keep(r[14], p14, km); ce_keep(r[15], p15, km);
}

__device__ __forceinline__ void stage_bperm64(u32 (&r)[NE], int addr, bool km) {
  stage_bperm16(*reinterpret_cast<u32(*)[16]>(&r[0]), addr, km);
  stage_bperm16(*reinterpret_cast<u32(*)[16]>(&r[16]), addr, km);
  stage_bperm16(*reinterpret_cast<u32(*)[16]>(&r[32]), addr, km);
  stage_bperm16(*reinterpret_cast<u32(*)[16]>(&r[48]), addr, km);
}

// cross-lane stage m=1 (quad_perm [1,0,3,2] = 0xB1) / m=2 ([2,3,0,1] = 0x4E)
// via DPP: VALU only, no DS traffic.
template<int CTRL>
__device__ __forceinline__ void stage_dpp(u32 (&r)[NE], bool km) {
#pragma unroll
  for (int v = 0; v < NE; ++v) {
    u32 p = (u32)__builtin_amdgcn_update_dpp(0, (int)r[v], CTRL, 0xF, 0xF, true);
    u32 mn = pkmin(r[v], p), mx = pkmax(r[v], p);
    r[v] = km ? mn : mx;
  }
}

// ---------------- Kernel B: 4 independent waves/block; 64 elems/lane -----
// __launch_bounds__(256, 1): allow the RA the full 512-VGPR budget so the
// 64-reg sort state + 16 bpermute partners live in arch VGPRs with NO
// AGPR/scratch spill traffic (round-10: VGPR_Count=60 forced ~2x dynamic
// instruction bloat from spill moves).
__global__ __launch_bounds__(WPB * 64, 1) void dist_kernel(const float* __restrict__ x,
                                                           const float* __restrict__ y,
                                                           const float* __restrict__ theta,
                                                           float* __restrict__ dist) {
  const int unit = blockIdx.x * WPB + (threadIdx.x >> 6);  // (b,l) unit
  const int l = unit & (NL - 1);
  const int b = unit >> 7;
  const int lane = threadIdx.x & 63;

  const float* tp = theta + ((size_t)l * NB + b) * 3;
  const float t0 = tp[0];
  const float t1 = tp[1];
  const float t2 = tp[2];

  // load 64 consecutive points from each array, project, pack (x|y) per reg
  u32 r[NE];
  {
    const float4* px = (const float4*)(x + (size_t)b * NP * ND + (size_t)lane * 192);
    const float4* py = (const float4*)(y + (size_t)b * NP * ND + (size_t)lane * 192);
#pragma unroll
    for (int g = 0; g < 16; ++g) {
      float4 XA = px[3 * g], XB = px[3 * g + 1], XC = px[3 * g + 2];
      float4 YA = py[3 * g], YB = py[3 * g + 1], YC = py[3 * g + 2];
      float x0 = XA.x * t0 + XA.y * t1 + XA.z * t2;
      float x1 = XA.w * t0 + XB.x * t1 + XB.y * t2;
      float x2 = XB.z * t0 + XB.w * t1 + XC.x * t2;
      float x3 = XC.y * t0 + XC.z * t1 + XC.w * t2;
      float y0 = YA.x * t0 + YA.y * t1 + YA.z * t2;
      float y1 = YA.w * t0 + YB.x * t1 + YB.y * t2;
      float y2 = YB.z * t0 + YB.w * t1 + YC.x * t2;
      float y3 = YC.y * t0 + YC.z * t1 + YC.w * t2;
      r[4 * g + 0] = __builtin_bit_cast(u32, __builtin_amdgcn_cvt_pkrtz(x0, y0));
      r[4 * g + 1] = __builtin_bit_cast(u32, __builtin_amdgcn_cvt_pkrtz(x1, y1));
      r[4 * g + 2] = __builtin_bit_cast(u32, __builtin_amdgcn_cvt_pkrtz(x2, y2));
      r[4 * g + 3] = __builtin_bit_cast(u32, __builtin_amdgcn_cvt_pkrtz(x3, y3));
    }
  }

  // element i = lane*64 + v.  static phases k=2..32 (true domain, dir from v)
#pragma unroll
  for (int k = 2; k <= 32; k <<= 1)
#pragma unroll
    for (int j = k >> 1; j >= 1; j >>= 1)
#pragma unroll
      for (int v = 0; v < NE; ++v)
        if (!(v & j)) {
          if (!(v & k)) ceA(r[v], r[v | j]);
          else          ceD(r[v], r[v | j]);
        }

  // phase k=64: dir bit = i&64 = lane&1 -> flip, ascending tail
  flip64(r, fmask((u32)lane & 1u));
  tail64(r);

  // phases k=128..4096 (p=0..5): flip delta, cross-lane m=2^p..1, tail
  const int lanesh2 = lane << 2;
#pragma unroll 1
  for (int p = 0; p < 6; ++p) {
    flip64(r, fmask(((u32)(lane >> p) ^ (u32)(lane >> (p + 1))) & 1u));
#pragma unroll 1
    for (int m = 1 << p; m >= 4; m >>= 1)
      stage_bperm64(r, lanesh2 ^ (m << 2), (lane & m) == 0);
    if (p >= 1) stage_dpp<0x4E>(r, (lane & 2) == 0);  // m=2
    stage_dpp<0xB1>(r, (lane & 1) == 0);              // m=1
    tail64(r);
  }

  // epilogue: sum (xs_i - ys_i)^2 = (lo16 - hi16)^2 per reg, wave-reduce
  float s = 0.0f;
#pragma unroll
  for (int w = 0; w < NE; ++w) {
    half2v h = __builtin_bit_cast(half2v, r[w]);
    float d = (float)h[0] - (float)h[1];
    s = fmaf(d, d, s);
  }
#pragma unroll
  for (int off = 32; off; off >>= 1) s += __shfl_down(s, off, 64);
  if (lane == 0) dist[l * NB + b] = s;
}

// ---------------- Kernel C: IMH chain + loss reduction ----------------
__global__ __launch_bounds__(64) void chain_kernel(const float* __restrict__ dist,
                                                   const float* __restrict__ logu,
                                                   float* __restrict__ out) {
  const int b = threadIdx.x;
  float dold = dist[b];  // l = 0
  float sum = dold;
  for (int l = 1; l < NL; ++l) {
    float dn = dist[l * NB + b];
    float acc = fminf(0.0f, dn - dold);
    if (logu[l * NB + b] <= acc) dold = dn;
    sum += dold;
  }
  float v = sqrtf(sum * (1.0f / (float)NL));
  for (int off = 32; off; off >>= 1) v += __shfl_down(v, off, 64);
  if (b == 0) out[0] = v * (1.0f / (float)NB);
}

extern "C" void kernel_launch(void* const* d_in, const int* in_sizes, int n_in,
                              void* d_out, int out_size, void* d_ws, size_t ws_size,
                              hipStream_t stream) {
  const float* x = (const float*)d_in[0];
  const float* y = (const float*)d_in[1];
  float* out = (float*)d_out;

  float* theta = (float*)d_ws;              // NL*NB*3 floats
  float* logu = theta + NL * NB * 3;        // NL*NB floats
  float* dist = logu + NL * NB;             // NL*NB floats

  hipLaunchKernelGGL(rng_kernel, dim3(NL), dim3(128), 0, stream, theta, logu);
  hipLaunchKernelGGL(dist_kernel, dim3(NB * NL / WPB), dim3(WPB * 64), 0, stream,
                     x, y, theta, dist);
  hipLaunchKernelGGL(chain_kernel, dim3(1), dim3(64), 0, stream, dist, logu, out);
}

// Round 13
// 231.829 us; speedup vs baseline: 1.0088x; 1.0088x over previous
//
#include <hip/hip_runtime.h>
#include <stdint.h>

#define NB 64     // batch
#define NP 4096   // points per batch
#define ND 3      // dim
#define NL 128    // chain length / projections
#define NE 64     // elements per lane; one wave handles one (b,l) unit
#define WPB 4     // independent waves (units) per block

typedef uint32_t u32;
typedef _Float16 half2v __attribute__((ext_vector_type(2)));

// ---------------- JAX threefry2x32 (20 rounds) ----------------
__device__ __forceinline__ uint32_t rotl32(uint32_t v, int r) {
  return (v << r) | (v >> (32 - r));
}

__device__ __forceinline__ void threefry2x32(uint32_t k0, uint32_t k1,
                                             uint32_t c0, uint32_t c1,
                                             uint32_t& o0, uint32_t& o1) {
  uint32_t ks2 = k0 ^ k1 ^ 0x1BD11BDAu;
  uint32_t x0 = c0 + k0;
  uint32_t x1 = c1 + k1;
#define TF_RND(R) { x0 += x1; x1 = rotl32(x1, (R)); x1 ^= x0; }
  TF_RND(13) TF_RND(15) TF_RND(26) TF_RND(6)
  x0 += k1;  x1 += ks2 + 1u;
  TF_RND(17) TF_RND(29) TF_RND(16) TF_RND(24)
  x0 += ks2; x1 += k0 + 2u;
  TF_RND(13) TF_RND(15) TF_RND(26) TF_RND(6)
  x0 += k0;  x1 += k1 + 3u;
  TF_RND(17) TF_RND(29) TF_RND(16) TF_RND(24)
  x0 += k1;  x1 += ks2 + 4u;
  TF_RND(13) TF_RND(15) TF_RND(26) TF_RND(6)
  x0 += ks2; x1 += k0 + 5u;
#undef TF_RND
  o0 = x0; o1 = x1;
}

// ---------------- XLA ErfInv32 ----------------
__device__ __forceinline__ float erfinv_f(float x) {
  float w = -log1pf(-x * x);
  float p;
  if (w < 5.0f) {
    w = w - 2.5f;
    p = 2.81022636e-08f;
    p = fmaf(p, w, 3.43273939e-07f);
    p = fmaf(p, w, -3.5233877e-06f);
    p = fmaf(p, w, -4.39150654e-06f);
    p = fmaf(p, w, 0.00021858087f);
    p = fmaf(p, w, -0.00125372503f);
    p = fmaf(p, w, -0.00417768164f);
    p = fmaf(p, w, 0.246640727f);
    p = fmaf(p, w, 1.50140941f);
  } else {
    w = sqrtf(w) - 3.0f;
    p = -0.000200214257f;
    p = fmaf(p, w, 0.000100950558f);
    p = fmaf(p, w, 0.00134934322f);
    p = fmaf(p, w, -0.00367342844f);
    p = fmaf(p, w, 0.00573950773f);
    p = fmaf(p, w, -0.0076224613f);
    p = fmaf(p, w, 0.00943887047f);
    p = fmaf(p, w, 1.00167406f);
    p = fmaf(p, w, 2.83297682f);
  }
  return p * x;
}

__device__ __forceinline__ float bits_to_normal(uint32_t bits) {
  float f = __uint_as_float((bits >> 9) | 0x3F800000u) - 1.0f;  // [0,1)
  const float LO = -0.99999994f;  // nextafter(-1, 0)
  float u = fmaf(f, 2.0f, LO);
  u = fmaxf(LO, u);
  return 1.41421354f * erfinv_f(u);
}

__device__ __forceinline__ float bits_to_unif01(uint32_t bits) {
  float f = __uint_as_float((bits >> 9) | 0x3F800000u) - 1.0f;
  return fmaxf(0.0f, f);
}

// ---------------- Kernel A: thetas (normalized) + log-uniforms ----------
__global__ __launch_bounds__(128) void rng_kernel(float* __restrict__ theta,
                                                  float* __restrict__ logu) {
  const int l = blockIdx.x;
  const int tid = threadIdx.x;

  uint32_t kl0, kl1;
  threefry2x32(0u, 42u, 0u, (uint32_t)l, kl0, kl1);

  uint32_t na0 = kl0, na1 = kl1;
  uint32_t nb0 = 0u, nb1 = 0u;
  if (l > 0) {
    uint32_t a0, b0, a1, b1;
    threefry2x32(kl0, kl1, 0u, 2u, a0, b0);
    threefry2x32(kl0, kl1, 1u, 3u, a1, b1);
    na0 = a0; na1 = a1;
    nb0 = b0; nb1 = b1;
  }

  __shared__ float vals[NB * ND];
  if (tid < 96) {
    uint32_t o0, o1;
    threefry2x32(na0, na1, (uint32_t)tid, (uint32_t)(96 + tid), o0, o1);
    vals[tid] = bits_to_normal(o0);
    vals[96 + tid] = bits_to_normal(o1);
  }
  __syncthreads();

  if (tid < NB) {
    float v0 = vals[tid * 3 + 0];
    float v1 = vals[tid * 3 + 1];
    float v2 = vals[tid * 3 + 2];
    float s = sqrtf(v0 * v0 + v1 * v1 + v2 * v2);
    float* tp = theta + ((size_t)l * NB + tid) * 3;
    tp[0] = v0 / s;
    tp[1] = v1 / s;
    tp[2] = v2 / s;
  }

  if (l > 0 && tid < 32) {
    uint32_t o0, o1;
    threefry2x32(nb0, nb1, (uint32_t)tid, (uint32_t)(32 + tid), o0, o1);
    logu[l * NB + tid] = logf(bits_to_unif01(o0));
    logu[l * NB + 32 + tid] = logf(bits_to_unif01(o1));
  }
}

// ---------------- packed primitives ----------------
__device__ __forceinline__ u32 pkmin(u32 a, u32 b) {
  u32 d; asm("v_pk_min_f16 %0, %1, %2" : "=v"(d) : "v"(a), "v"(b)); return d;
}
__device__ __forceinline__ u32 pkmax(u32 a, u32 b) {
  u32 d; asm("v_pk_max_f16 %0, %1, %2" : "=v"(d) : "v"(a), "v"(b)); return d;
}

__device__ __forceinline__ void ceA(u32& a, u32& b) {
  u32 mn = pkmin(a, b), mx = pkmax(a, b); a = mn; b = mx;
}
__device__ __forceinline__ void ceD(u32& a, u32& b) {
  u32 mn = pkmin(a, b), mx = pkmax(a, b); a = mx; b = mn;
}

__device__ __forceinline__ u32 fmask(u32 d) {  // d in {0,1}
  return (d << 31) | (d << 15);
}

__device__ __forceinline__ void flip64(u32 (&r)[NE], u32 mask) {
#pragma unroll
  for (int w = 0; w < NE; ++w) r[w] ^= mask;
}

// in-thread ascending tail: stages j = 32,16,8,4,2,1 over the 64 regs
__device__ __forceinline__ void tail64(u32 (&r)[NE]) {
#pragma unroll
  for (int j = 32; j >= 1; j >>= 1)
#pragma unroll
    for (int v = 0; v < NE; ++v)
      if (!(v & j)) ceA(r[v], r[v | j]);
}

__device__ __forceinline__ void ce_keep(u32& a, u32 p, bool km) {
  u32 mn = pkmin(a, p), mx = pkmax(a, p);
  a = km ? mn : mx;
}

// 16 ds_bpermute in one asm block, single waitcnt (validated rounds 5/8/9).
// Takes 16 individual scalar references -- NO address-taking of the r[]
// array (round-12: reinterpret_cast<u32(*)[16]>(&r[16]) address exposure is
// a suspect for the RA parking the sort state in AGPRs).
__device__ __forceinline__ void stage_bperm16(
    u32& r0, u32& r1, u32& r2, u32& r3, u32& r4, u32& r5, u32& r6, u32& r7,
    u32& r8, u32& r9, u32& r10, u32& r11, u32& r12, u32& r13, u32& r14,
    u32& r15, int addr, bool km) {
  u32 p0, p1, p2, p3, p4, p5, p6, p7, p8, p9, p10, p11, p12, p13, p14, p15;
  asm("ds_bpermute_b32 %0, %16, %17\n\t"
      "ds_bpermute_b32 %1, %16, %18\n\t"
      "ds_bpermute_b32 %2, %16, %19\n\t"
      "ds_bpermute_b32 %3, %16, %20\n\t"
      "ds_bpermute_b32 %4, %16, %21\n\t"
      "ds_bpermute_b32 %5, %16, %22\n\t"
      "ds_bpermute_b32 %6, %16, %23\n\t"
      "ds_bpermute_b32 %7, %16, %24\n\t"
      "ds_bpermute_b32 %8, %16, %25\n\t"
      "ds_bpermute_b32 %9, %16, %26\n\t"
      "ds_bpermute_b32 %10, %16, %27\n\t"
      "ds_bpermute_b32 %11, %16, %28\n\t"
      "ds_bpermute_b32 %12, %16, %29\n\t"
      "ds_bpermute_b32 %13, %16, %30\n\t"
      "ds_bpermute_b32 %14, %16, %31\n\t"
      "ds_bpermute_b32 %15, %16, %32\n\t"
      "s_waitcnt lgkmcnt(0)"
      : "=&v"(p0), "=&v"(p1), "=&v"(p2), "=&v"(p3),
        "=&v"(p4), "=&v"(p5), "=&v"(p6), "=&v"(p7),
        "=&v"(p8), "=&v"(p9), "=&v"(p10), "=&v"(p11),
        "=&v"(p12), "=&v"(p13), "=&v"(p14), "=&v"(p15)
      : "v"(addr),
        "v"(r0), "v"(r1), "v"(r2), "v"(r3),
        "v"(r4), "v"(r5), "v"(r6), "v"(r7),
        "v"(r8), "v"(r9), "v"(r10), "v"(r11),
        "v"(r12), "v"(r13), "v"(r14), "v"(r15));
  ce_keep(r0, p0, km);   ce_keep(r1, p1, km);
  ce_keep(r2, p2, km);   ce_keep(r3, p3, km);
  ce_keep(r4, p4, km);   ce_keep(r5, p5, km);
  ce_keep(r6, p6, km);   ce_keep(r7, p7, km);
  ce_keep(r8, p8, km);   ce_keep(r9, p9, km);
  ce_keep(r10, p10, km); ce_keep(r11, p11, km);
  ce_keep(r12, p12, km); ce_keep(r13, p13, km);
  ce_keep(r14, p14, km); ce_keep(r15, p15, km);
}

__device__ __forceinline__ void stage_bperm64(u32 (&r)[NE], int addr, bool km) {
  stage_bperm16(r[0], r[1], r[2], r[3], r[4], r[5], r[6], r[7],
                r[8], r[9], r[10], r[11], r[12], r[13], r[14], r[15],
                addr, km);
  stage_bperm16(r[16], r[17], r[18], r[19], r[20], r[21], r[22], r[23],
                r[24], r[25], r[26], r[27], r[28], r[29], r[30], r[31],
                addr, km);
  stage_bperm16(r[32], r[33], r[34], r[35], r[36], r[37], r[38], r[39],
                r[40], r[41], r[42], r[43], r[44], r[45], r[46], r[47],
                addr, km);
  stage_bperm16(r[48], r[49], r[50], r[51], r[52], r[53], r[54], r[55],
                r[56], r[57], r[58], r[59], r[60], r[61], r[62], r[63],
                addr, km);
}

// cross-lane stage m=1 (quad_perm [1,0,3,2] = 0xB1) / m=2 ([2,3,0,1] = 0x4E)
// via DPP: VALU only, no DS traffic.
template<int CTRL>
__device__ __forceinline__ void stage_dpp(u32 (&r)[NE], bool km) {
#pragma unroll
  for (int v = 0; v < NE; ++v) {
    u32 p = (u32)__builtin_amdgcn_update_dpp(0, (int)r[v], CTRL, 0xF, 0xF, true);
    u32 mn = pkmin(r[v], p), mx = pkmax(r[v], p);
    r[v] = km ? mn : mx;
  }
}

// ---------------- Kernel B: 4 independent waves/block; 64 elems/lane -----
// amdgpu_waves_per_eu(1): directly tell the backend RA that 1 wave/EU is
// acceptable -> full register budget, no incentive to park the 64-reg sort
// state in AGPRs (round-12: launch_bounds(256,1) left VGPR_Count at 60 with
// ~110 AGPRs; occupancy arithmetic 2048/170 = 12 waves/CU = measured 38%).
__global__ __launch_bounds__(WPB * 64)
__attribute__((amdgpu_waves_per_eu(1)))
void dist_kernel(const float* __restrict__ x,
                 const float* __restrict__ y,
                 const float* __restrict__ theta,
                 float* __restrict__ dist) {
  const int unit = blockIdx.x * WPB + (threadIdx.x >> 6);  // (b,l) unit
  const int l = unit & (NL - 1);
  const int b = unit >> 7;
  const int lane = threadIdx.x & 63;

  const float* tp = theta + ((size_t)l * NB + b) * 3;
  const float t0 = tp[0];
  const float t1 = tp[1];
  const float t2 = tp[2];

  // load 64 consecutive points from each array, project, pack (x|y) per reg
  u32 r[NE];
  {
    const float4* px = (const float4*)(x + (size_t)b * NP * ND + (size_t)lane * 192);
    const float4* py = (const float4*)(y + (size_t)b * NP * ND + (size_t)lane * 192);
#pragma unroll
    for (int g = 0; g < 16; ++g) {
      float4 XA = px[3 * g], XB = px[3 * g + 1], XC = px[3 * g + 2];
      float4 YA = py[3 * g], YB = py[3 * g + 1], YC = py[3 * g + 2];
      float x0 = XA.x * t0 + XA.y * t1 + XA.z * t2;
      float x1 = XA.w * t0 + XB.x * t1 + XB.y * t2;
      float x2 = XB.z * t0 + XB.w * t1 + XC.x * t2;
      float x3 = XC.y * t0 + XC.z * t1 + XC.w * t2;
      float y0 = YA.x * t0 + YA.y * t1 + YA.z * t2;
      float y1 = YA.w * t0 + YB.x * t1 + YB.y * t2;
      float y2 = YB.z * t0 + YB.w * t1 + YC.x * t2;
      float y3 = YC.y * t0 + YC.z * t1 + YC.w * t2;
      r[4 * g + 0] = __builtin_bit_cast(u32, __builtin_amdgcn_cvt_pkrtz(x0, y0));
      r[4 * g + 1] = __builtin_bit_cast(u32, __builtin_amdgcn_cvt_pkrtz(x1, y1));
      r[4 * g + 2] = __builtin_bit_cast(u32, __builtin_amdgcn_cvt_pkrtz(x2, y2));
      r[4 * g + 3] = __builtin_bit_cast(u32, __builtin_amdgcn_cvt_pkrtz(x3, y3));
    }
  }

  // element i = lane*64 + v.  static phases k=2..32 (true domain, dir from v)
#pragma unroll
  for (int k = 2; k <= 32; k <<= 1)
#pragma unroll
    for (int j = k >> 1; j >= 1; j >>= 1)
#pragma unroll
      for (int v = 0; v < NE; ++v)
        if (!(v & j)) {
          if (!(v & k)) ceA(r[v], r[v | j]);
          else          ceD(r[v], r[v | j]);
        }

  // phase k=64: dir bit = i&64 = lane&1 -> flip, ascending tail
  flip64(r, fmask((u32)lane & 1u));
  tail64(r);

  // phases k=128..4096 (p=0..5): flip delta, cross-lane m=2^p..1, tail
  const int lanesh2 = lane << 2;
#pragma unroll 1
  for (int p = 0; p < 6; ++p) {
    flip64(r, fmask(((u32)(lane >> p) ^ (u32)(lane >> (p + 1))) & 1u));
#pragma unroll 1
    for (int m = 1 << p; m >= 4; m >>= 1)
      stage_bperm64(r, lanesh2 ^ (m << 2), (lane & m) == 0);
    if (p >= 1) stage_dpp<0x4E>(r, (lane & 2) == 0);  // m=2
    stage_dpp<0xB1>(r, (lane & 1) == 0);              // m=1
    tail64(r);
  }

  // epilogue: sum (xs_i - ys_i)^2 = (lo16 - hi16)^2 per reg, wave-reduce
  float s = 0.0f;
#pragma unroll
  for (int w = 0; w < NE; ++w) {
    half2v h = __builtin_bit_cast(half2v, r[w]);
    float d = (float)h[0] - (float)h[1];
    s = fmaf(d, d, s);
  }
#pragma unroll
  for (int off = 32; off; off >>= 1) s += __shfl_down(s, off, 64);
  if (lane == 0) dist[l * NB + b] = s;
}

// ---------------- Kernel C: IMH chain + loss reduction ----------------
__global__ __launch_bounds__(64) void chain_kernel(const float* __restrict__ dist,
                                                   const float* __restrict__ logu,
                                                   float* __restrict__ out) {
  const int b = threadIdx.x;
  float dold = dist[b];  // l = 0
  float sum = dold;
  for (int l = 1; l < NL; ++l) {
    float dn = dist[l * NB + b];
    float acc = fminf(0.0f, dn - dold);
    if (logu[l * NB + b] <= acc) dold = dn;
    sum += dold;
  }
  float v = sqrtf(sum * (1.0f / (float)NL));
  for (int off = 32; off; off >>= 1) v += __shfl_down(v, off, 64);
  if (b == 0) out[0] = v * (1.0f / (float)NB);
}

extern "C" void kernel_launch(void* const* d_in, const int* in_sizes, int n_in,
                              void* d_out, int out_size, void* d_ws, size_t ws_size,
                              hipStream_t stream) {
  const float* x = (const float*)d_in[0];
  const float* y = (const float*)d_in[1];
  float* out = (float*)d_out;

  float* theta = (float*)d_ws;              // NL*NB*3 floats
  float* logu = theta + NL * NB * 3;        // NL*NB floats
  float* dist = logu + NL * NB;             // NL*NB floats

  hipLaunchKernelGGL(rng_kernel, dim3(NL), dim3(128), 0, stream, theta, logu);
  hipLaunchKernelGGL(dist_kernel, dim3(NB * NL / WPB), dim3(WPB * 64), 0, stream,
                     x, y, theta, dist);
  hipLaunchKernelGGL(chain_kernel, dim3(1), dim3(64), 0, stream, dist, logu, out);
}